// Round 12
// baseline (138.987 us; speedup 1.0000x reference)
//
#include <hip/hip_runtime.h>
#include <hip/hip_bf16.h>

#define BB 2
#define TT 2048
#define CC 1024
#define NHEAD 16
#define DHEAD 64
#define MM (BB*TT)

using bf16 = __hip_bfloat16;
typedef __bf16 bf16x8 __attribute__((ext_vector_type(8)));
typedef float f32x4 __attribute__((ext_vector_type(4)));
typedef float f32x16 __attribute__((ext_vector_type(16)));

static __device__ __forceinline__ bf16 f2b(float f) { return __float2bfloat16(f); }
static __device__ __forceinline__ float fast_exp2(float f) { return __builtin_amdgcn_exp2f(f); }
static __device__ __forceinline__ unsigned pack2(float a, float b) {
  __bf16 x = (__bf16)a, y = (__bf16)b;
  unsigned short ux = __builtin_bit_cast(unsigned short, x);
  unsigned short uy = __builtin_bit_cast(unsigned short, y);
  return ((unsigned)uy << 16) | ux;
}

// async global -> LDS, 16B per lane (dest wave-uniform base; HW adds lane*16B)
static __device__ __forceinline__ void gload16(const bf16* g, bf16* l) {
  __builtin_amdgcn_global_load_lds((__attribute__((address_space(1))) const void*)g,
                                   (__attribute__((address_space(3))) void*)l, 16, 0, 0);
}

// ------------- fused prep: x->bf16 convert + Wqkv^T + Wproj^T -------------
__global__ __launch_bounds__(256)
void k_prep(const float* __restrict__ x, bf16* __restrict__ Xb,
            const float* __restrict__ Wqkv, bf16* __restrict__ WqkvT,
            const float* __restrict__ Wproj, bf16* __restrict__ WprojT)
{
  int bid = blockIdx.x;
  const int tid = threadIdx.x;
  if (bid < 1024) {
    int base = bid * 1024 + tid;
#pragma unroll
    for (int k = 0; k < 4; ++k) {
      int i = base + k * 256;
      float4 v = reinterpret_cast<const float4*>(x)[i];
      bf16 o[4] = { f2b(v.x), f2b(v.y), f2b(v.z), f2b(v.w) };
      reinterpret_cast<uint2*>(Xb)[i] = *reinterpret_cast<uint2*>(o);
    }
    return;
  }
  bid -= 1024;
  __shared__ float tile[32][33];
  const float* W; bf16* WT; int R, Cc, bx, by;
  if (bid < 3072) {
    W = Wqkv;  WT = WqkvT;  R = CC; Cc = 3*CC;
    bx = bid % 96; by = bid / 96;
  } else {
    bid -= 3072;
    W = Wproj; WT = WprojT; R = CC; Cc = CC;
    bx = bid % 32; by = bid / 32;
  }
  int c0 = bx * 32, r0 = by * 32;
  int tx = tid & 31, ty = tid >> 5;
#pragma unroll
  for (int i = 0; i < 4; ++i)
    tile[ty + 8*i][tx] = W[(size_t)(r0 + ty + 8*i) * Cc + c0 + tx];
  __syncthreads();
#pragma unroll
  for (int i = 0; i < 4; ++i)
    WT[(size_t)(c0 + ty + 8*i) * R + r0 + tx] = f2b(tile[tx][ty + 8*i]);
}

// ------------- per-head V (T x D) -> V^T (D x T), bf16 -------------
__global__ void k_vtrans(const bf16* __restrict__ V, bf16* __restrict__ VT) {
  __shared__ bf16 tile[32][33];
  const int bn = blockIdx.z;
  const int d0 = blockIdx.x * 32, t0 = blockIdx.y * 32;
  const size_t base = (size_t)bn * TT * DHEAD;
  int tx = threadIdx.x, ty = threadIdx.y;
#pragma unroll
  for (int i = 0; i < 4; ++i)
    tile[ty + 8*i][tx] = V[base + (size_t)(t0 + ty + 8*i) * DHEAD + d0 + tx];
  __syncthreads();
#pragma unroll
  for (int i = 0; i < 4; ++i)
    VT[base + (size_t)(d0 + ty + 8*i) * TT + t0 + tx] = tile[tx][ty + 8*i];
}

// ============ QKV GEMM (R11, unchanged) ============
#define NTK 32
__global__ __launch_bounds__(512, 2)
void k_gemm_qkv(const bf16* __restrict__ Ag, const bf16* __restrict__ Bg,
                const float* __restrict__ bias,
                bf16* __restrict__ Qb, bf16* __restrict__ Kb, bf16* __restrict__ Vb)
{
  const int tid = threadIdx.x;
  const int w = tid >> 6, l = tid & 63;
  const int l16 = l & 15, l4 = l >> 4;
  const int wr = w >> 2, wc = w & 3;

  const int flat = blockIdx.x;
  const int xcd = flat & 7, local = flat >> 3;
  const int bx = (xcd & 1) * 6 + local % 6;
  const int by = (xcd >> 1) * 8 + local / 6;
  const int m0 = by * 128, n0 = bx * 256;

  __shared__ __align__(16) bf16 sm[36864];

  f32x4 acc[4][4];
#pragma unroll
  for (int m = 0; m < 4; ++m)
#pragma unroll
    for (int n = 0; n < 4; ++n) acc[m][n] = 0.f;

  const int srow = tid >> 2;
  const int scol = ((tid & 3) ^ ((tid >> 3) & 3)) * 8;

#define STAGE(buf, kt) do {                                                            \
    const int kb = (kt) * 32 + scol;                                                   \
    gload16(&Ag[(size_t)(m0 +       srow) * CC + kb], &sm[(buf)*12288        + w*512]);\
    gload16(&Bg[(size_t)(n0 +       srow) * CC + kb], &sm[(buf)*12288 + 4096 + w*512]);\
    gload16(&Bg[(size_t)(n0 + 128 + srow) * CC + kb], &sm[(buf)*12288 + 8192 + w*512]);\
  } while (0)

  STAGE(0, 0);
  STAGE(1, 1);
  STAGE(2, 2);
  asm volatile("s_waitcnt vmcnt(6)" ::: "memory");
  __builtin_amdgcn_s_barrier();

  const int slotA = (l4 ^ ((l16 >> 1) & 3)) * 8;
  const int aoff = wr * 2048 + l16 * 32 + slotA;
  const int boff = 4096 + wc * 2048 + l16 * 32 + slotA;

  int rb = 0;
  for (int kt = 0; kt < NTK; ++kt) {
    const int base = rb * 12288;

    bf16x8 af[4], bfr[4];
#pragma unroll
    for (int m = 0; m < 4; ++m)
      af[m] = *reinterpret_cast<const bf16x8*>(&sm[base + aoff + m*512]);
#pragma unroll
    for (int n = 0; n < 4; ++n)
      bfr[n] = *reinterpret_cast<const bf16x8*>(&sm[base + boff + n*512]);
    __builtin_amdgcn_s_setprio(1);
#pragma unroll
    for (int m = 0; m < 4; ++m)
#pragma unroll
      for (int n = 0; n < 4; ++n)
        acc[m][n] = __builtin_amdgcn_mfma_f32_16x16x32_bf16(af[m], bfr[n], acc[m][n], 0, 0, 0);
    __builtin_amdgcn_s_setprio(0);

    __builtin_amdgcn_s_barrier();
    if (kt + 3 < NTK) {
      STAGE(rb, kt + 3);
      asm volatile("s_waitcnt vmcnt(6)" ::: "memory");
    } else if (kt + 2 < NTK) {
      asm volatile("s_waitcnt vmcnt(3)" ::: "memory");
    } else if (kt + 1 < NTK) {
      asm volatile("s_waitcnt vmcnt(0)" ::: "memory");
    }
    __builtin_amdgcn_s_barrier();
    rb = (rb + 1 == 3) ? 0 : rb + 1;
  }
#undef STAGE

  const int ccol = n0 + wc * 64;
  const int which = ccol >> 10;
  bf16* __restrict__ dst = (which == 0) ? Qb : (which == 1) ? Kb : Vb;
  const float qsc = (which == 0) ? 0.125f * 1.4426950408889634f : 1.0f;
#pragma unroll
  for (int m = 0; m < 4; ++m)
#pragma unroll
    for (int n = 0; n < 4; ++n) {
      int gc = ccol + n*16 + l16;
      float bv = bias[gc];
      int c = gc & (CC-1), head = c >> 6, d = c & 63;
#pragma unroll
      for (int j = 0; j < 4; ++j) {
        int gr = m0 + wr*64 + m*16 + l4*4 + j;
        int b = gr >> 11, t = gr & (TT-1);
        dst[(((size_t)b*NHEAD + head)*TT + t)*DHEAD + d] = f2b((acc[m][n][j] + bv) * qsc);
      }
    }
}

// ---------------- proj GEMM (m97 structure + XCD swizzle, unchanged) ----------------
__global__ __launch_bounds__(256)
void k_gemm_proj(const bf16* __restrict__ A, const bf16* __restrict__ Bt,
                 const float* __restrict__ bias, float* __restrict__ outF, int K)
{
  const int tid  = threadIdx.x;
  const int wave = tid >> 6, lane = tid & 63;
  const int l16 = lane & 15, l4 = lane >> 4;
  const int wr = wave >> 1, wc = wave & 1;

  const int gx = gridDim.x;
  const int flat = blockIdx.y * gx + blockIdx.x;
  const int cpx = (gx * gridDim.y) >> 3;
  const int swz = (flat & 7) * cpx + (flat >> 3);
  const int bx = swz % gx, by = swz / gx;
  const int m0 = by * 128, n0 = bx * 128;

  __shared__ __align__(16) bf16 As[128*32];
  __shared__ __align__(16) bf16 Bs[128*32];

  f32x4 acc[4][4];
#pragma unroll
  for (int m = 0; m < 4; ++m)
#pragma unroll
    for (int n = 0; n < 4; ++n) acc[m][n] = 0.f;

  const int sr = tid >> 2;
  const int sc = (tid & 3) * 8;

  for (int k0 = 0; k0 < K; k0 += 32) {
    __syncthreads();
#pragma unroll
    for (int i = 0; i < 2; ++i) {
      gload16(&A [(size_t)(m0 + i*64 + sr) * K + k0 + sc], &As[i*2048 + tid*8]);
      gload16(&Bt[(size_t)(n0 + i*64 + sr) * K + k0 + sc], &Bs[i*2048 + tid*8]);
    }
    __syncthreads();
    bf16x8 af[4], bfr[4];
#pragma unroll
    for (int m = 0; m < 4; ++m)
      af[m] = *reinterpret_cast<const bf16x8*>(&As[(wr*64 + m*16 + l16)*32 + l4*8]);
#pragma unroll
    for (int n = 0; n < 4; ++n)
      bfr[n] = *reinterpret_cast<const bf16x8*>(&Bs[(wc*64 + n*16 + l16)*32 + l4*8]);
#pragma unroll
    for (int m = 0; m < 4; ++m)
#pragma unroll
      for (int n = 0; n < 4; ++n)
        acc[m][n] = __builtin_amdgcn_mfma_f32_16x16x32_bf16(af[m], bfr[n], acc[m][n], 0, 0, 0);
  }

#pragma unroll
  for (int m = 0; m < 4; ++m)
#pragma unroll
    for (int n = 0; n < 4; ++n)
#pragma unroll
      for (int j = 0; j < 4; ++j) {
        int gr = m0 + wr*64 + m*16 + l4*4 + j;
        int gc = n0 + wc*64 + n*16 + l16;
        outF[(size_t)gr * CC + gc] = acc[m][n][j] + bias[gc];
      }
}

// ---------------- flash attention v9: 32x32 MFMA, P fully in-register ----------------
// 4 waves x 32 q = 128-q tile; KVB=128 staged (two 64-kv passes); swapped QK^T with
// mfma_32x32x16 (S^T: col=q=lane&31, row=crow(r,hi)=(r&3)+8*(r>>2)+4*hi); softmax fully
// lane-local (1 shfl per reduce); P packed to bf16 in-register, half-exchange via
// shfl_xor(32)+select, fed as PV B-operand; O^T accum; epilogue transpose via LDS.
__global__ __launch_bounds__(256, 2)
void k_attn(const bf16* __restrict__ Qg, const bf16* __restrict__ Kg,
            const bf16* __restrict__ VTg, bf16* __restrict__ Aout)
{
  const int tid = threadIdx.x;
  const int w = tid >> 6, l = tid & 63;
  const int l32 = l & 31, hi = l >> 5;

  const int flat = blockIdx.x;               // 0..511; 8 XCDs x 64, 4 heads/XCD
  const int xcd = flat & 7, i6 = flat >> 3;
  const int bn = xcd*4 + (i6 >> 4);
  const int q0 = (i6 & 15) * 128;
  const int b = bn >> 4, h = bn & (NHEAD-1);

  __shared__ __align__(16) bf16 Ks[128][72];    // [kv][d]; reused as O-transpose buffer
  __shared__ __align__(16) bf16 Vt[64][136];    // [d][kv]

  const size_t hb = (size_t)bn * TT * DHEAD;
  const bf16* __restrict__ Kbase = Kg + hb;
  const bf16* __restrict__ Vbase = VTg + hb;

  // Q frags (PV-B-style layout): col q = l32, k(d) = kk*16 + hi*8 .. +7
  bf16x8 qf[4];
#pragma unroll
  for (int kk = 0; kk < 4; ++kk)
    qf[kk] = *reinterpret_cast<const bf16x8*>(
        &Qg[hb + (size_t)(q0 + w*32 + l32) * DHEAD + kk*16 + hi*8]);

  f32x16 o0, o1;                 // O^T[d][q=l32]; d = crow(r,hi) + 32*dblk
  o0 = 0.f; o1 = 0.f;
  float mrun = -1e30f, lrun = 0.f;

  // staging: Ks 128x64 (row tid>>1, 32 cols), Vt 64x128 (row tid>>2, 32 cols)
  const int krow = tid >> 1, kcol = (tid & 1) * 32;
  const int vrow = tid >> 2, vcol = (tid & 3) * 32;

  bf16x8 kreg[4], vreg[4];
#pragma unroll
  for (int i = 0; i < 4; ++i) {
    kreg[i] = *reinterpret_cast<const bf16x8*>(&Kbase[(size_t)krow * DHEAD + kcol + 8*i]);
    vreg[i] = *reinterpret_cast<const bf16x8*>(&Vbase[(size_t)vrow * TT + vcol + 8*i]);
  }
#pragma unroll
  for (int i = 0; i < 4; ++i) {
    *reinterpret_cast<bf16x8*>(&Ks[krow][kcol + 8*i]) = kreg[i];
    *reinterpret_cast<bf16x8*>(&Vt[vrow][vcol + 8*i]) = vreg[i];
  }

  for (int t0 = 0; t0 < TT; t0 += 128) {
    __syncthreads();                      // staged tile visible
    const bool more = (t0 + 128 < TT);
    if (more) {                           // T14: issue next-tile loads now, commit later
#pragma unroll
      for (int i = 0; i < 4; ++i) {
        kreg[i] = *reinterpret_cast<const bf16x8*>(
            &Kbase[(size_t)(t0 + 128 + krow) * DHEAD + kcol + 8*i]);
        vreg[i] = *reinterpret_cast<const bf16x8*>(
            &Vbase[(size_t)vrow * TT + t0 + 128 + vcol + 8*i]);
      }
    }

#pragma unroll
    for (int t64 = 0; t64 < 2; ++t64) {
      // ---- QK: S^T tiles (kv halves 0-31, 32-63 of this 64-kv subtile) ----
      f32x16 st0, st1;
      st0 = 0.f; st1 = 0.f;
      __builtin_amdgcn_s_setprio(1);
#pragma unroll
      for (int kk = 0; kk < 4; ++kk) {
        bf16x8 kf0 = *reinterpret_cast<const bf16x8*>(&Ks[t64*64 +      l32][kk*16 + hi*8]);
        bf16x8 kf1 = *reinterpret_cast<const bf16x8*>(&Ks[t64*64 + 32 + l32][kk*16 + hi*8]);
        st0 = __builtin_amdgcn_mfma_f32_32x32x16_bf16(kf0, qf[kk], st0, 0, 0, 0);
        st1 = __builtin_amdgcn_mfma_f32_32x32x16_bf16(kf1, qf[kk], st1, 0, 0, 0);
      }
      __builtin_amdgcn_s_setprio(0);

      // ---- softmax (exp2 domain), lane-local stats for q = l32 ----
      float pm = st0[0];
#pragma unroll
      for (int r = 1; r < 16; ++r) pm = fmaxf(pm, st0[r]);
#pragma unroll
      for (int r = 0; r < 16; ++r) pm = fmaxf(pm, st1[r]);
      pm = fmaxf(pm, __shfl_xor(pm, 32, 64));

      if (!__all(pm <= mrun + 8.f)) {
        float mn = fmaxf(mrun, pm);
        float corr = fast_exp2(mrun - mn);
        mrun = mn; lrun *= corr;
#pragma unroll
        for (int r = 0; r < 16; ++r) { o0[r] *= corr; o1[r] *= corr; }
      }

      float p0[16], p1[16];
      float ps = 0.f;
#pragma unroll
      for (int r = 0; r < 16; ++r) { p0[r] = fast_exp2(st0[r] - mrun); ps += p0[r]; }
#pragma unroll
      for (int r = 0; r < 16; ++r) { p1[r] = fast_exp2(st1[r] - mrun); ps += p1[r]; }
      ps += __shfl_xor(ps, 32, 64);
      lrun += ps;

      // ---- PV: O^T += V^T . P^T, P assembled in-register ----
      // chunk words: W0=(A0|B0s), W1=(A1|B1s), W2=(A0s|B0), W3=(A1s|B1) by hi
#define PV_CHUNK(P, s, koff)                                                       \
      {                                                                            \
        unsigned A0 = pack2(P[(s)+0], P[(s)+1]);                                   \
        unsigned A1 = pack2(P[(s)+2], P[(s)+3]);                                   \
        unsigned B0 = pack2(P[(s)+4], P[(s)+5]);                                   \
        unsigned B1 = pack2(P[(s)+6], P[(s)+7]);                                   \
        unsigned A0s = __shfl_xor(A0, 32, 64);                                     \
        unsigned A1s = __shfl_xor(A1, 32, 64);                                     \
        unsigned B0s = __shfl_xor(B0, 32, 64);                                     \
        unsigned B1s = __shfl_xor(B1, 32, 64);                                     \
        union { unsigned u[4]; bf16x8 v; } bw;                                     \
        bw.u[0] = hi ? B0s : A0;                                                   \
        bw.u[1] = hi ? B1s : A1;                                                   \
        bw.u[2] = hi ? B0  : A0s;                                                  \
        bw.u[3] = hi ? B1  : A1s;                                                  \
        bf16x8 vf0 = *reinterpret_cast<const bf16x8*>(&Vt[     l32][(koff) + hi*8]); \
        bf16x8 vf1 = *reinterpret_cast<const bf16x8*>(&Vt[32 + l32][(koff) + hi*8]); \
        __builtin_amdgcn_s_setprio(1);                                             \
        o0 = __builtin_amdgcn_mfma_f32_32x32x16_bf16(vf0, bw.v, o0, 0, 0, 0);      \
        o1 = __builtin_amdgcn_mfma_f32_32x32x16_bf16(vf1, bw.v, o1, 0, 0, 0);      \
        __builtin_amdgcn_s_setprio(0);                                             \
      }
      PV_CHUNK(p0, 0, t64*64 +  0)
      PV_CHUNK(p0, 8, t64*64 + 16)
      PV_CHUNK(p1, 0, t64*64 + 32)
      PV_CHUNK(p1, 8, t64*64 + 48)
#undef PV_CHUNK
    }

    __syncthreads();                      // all waves done reading Ks/Vt
    if (more) {
#pragma unroll
      for (int i = 0; i < 4; ++i) {
        *reinterpret_cast<bf16x8*>(&Ks[krow][kcol + 8*i]) = kreg[i];
        *reinterpret_cast<bf16x8*>(&Vt[vrow][vcol + 8*i]) = vreg[i];
      }
    }
  }

  // ---- epilogue: O^T -> LDS transpose (reusing Ks) -> coalesced store ----
  __syncthreads();                        // everyone done with Ks
  {
    float linv = 1.0f / lrun;
    unsigned* OL = reinterpret_cast<unsigned*>(&Ks[0][0]);   // pitch 36 u32/row
    const int qrow = w*32 + l32;
#pragma unroll
    for (int dblk = 0; dblk < 2; ++dblk)
#pragma unroll
      for (int r = 0; r < 16; r += 2) {
        int d = (r & 3) + 8*(r >> 2) + 4*hi + 32*dblk;
        float va = (dblk ? o1[r]   : o0[r])   * linv;
        float vb = (dblk ? o1[r+1] : o0[r+1]) * linv;
        OL[qrow*36 + (d >> 1)] = pack2(va, vb);
      }
  }
  __syncthreads();
  {
    const bf16* OLb = reinterpret_cast<const bf16*>(&Ks[0][0]);
    int row = tid >> 1, c0 = (tid & 1) * 32;
    size_t dst = (size_t)(b*TT + q0 + row) * CC + h*DHEAD + c0;
#pragma unroll
    for (int i = 0; i < 4; ++i)
      *reinterpret_cast<bf16x8*>(&Aout[dst + 8*i]) =
          *reinterpret_cast<const bf16x8*>(&OLb[row*72 + c0 + 8*i]);
  }
}

extern "C" void kernel_launch(void* const* d_in, const int* in_sizes, int n_in,
                              void* d_out, int out_size, void* d_ws, size_t ws_size,
                              hipStream_t stream)
{
  const float* x     = (const float*)d_in[0];
  const float* Wqkv  = (const float*)d_in[1];
  const float* bqkv  = (const float*)d_in[2];
  const float* Wproj = (const float*)d_in[3];
  const float* bproj = (const float*)d_in[4];
  float* out = (float*)d_out;

  char* p = (char*)d_ws;
  bf16* Xb     = (bf16*)p;  p += (size_t)MM*CC*2;
  bf16* WqkvT  = (bf16*)p;  p += (size_t)3*CC*CC*2;
  bf16* WprojT = (bf16*)p;  p += (size_t)CC*CC*2;
  bf16* Qb     = (bf16*)p;  p += (size_t)MM*CC*2;
  bf16* Kb     = (bf16*)p;  p += (size_t)MM*CC*2;
  bf16* Vb     = (bf16*)p;  p += (size_t)MM*CC*2;
  bf16* Attn   = (bf16*)p;  p += (size_t)MM*CC*2;
  bf16* VTb    = Xb;

  k_prep<<<5120, 256, 0, stream>>>(x, Xb, Wqkv, WqkvT, Wproj, WprojT);
  k_gemm_qkv<<<384, 512, 0, stream>>>(Xb, WqkvT, bqkv, Qb, Kb, Vb);
  k_vtrans<<<dim3(DHEAD/32, TT/32, BB*NHEAD), dim3(32, 8), 0, stream>>>(Vb, VTb);
  k_attn<<<512, 256, 0, stream>>>(Qb, Kb, VTb, Attn);
  k_gemm_proj<<<dim3(CC/128, MM/128), 256, 0, stream>>>(Attn, WprojT, bproj, out, CC);
}

// Round 13
// 124.137 us; speedup vs baseline: 1.1196x; 1.1196x over previous
//
#include <hip/hip_runtime.h>
#include <hip/hip_bf16.h>

#define BB 2
#define TT 2048
#define CC 1024
#define NHEAD 16
#define DHEAD 64
#define MM (BB*TT)
#define KVB 128

using bf16 = __hip_bfloat16;
typedef __bf16 bf16x8 __attribute__((ext_vector_type(8)));
typedef __bf16 bf16x4 __attribute__((ext_vector_type(4)));
typedef float f32x4 __attribute__((ext_vector_type(4)));

static __device__ __forceinline__ bf16 f2b(float f) { return __float2bfloat16(f); }
static __device__ __forceinline__ float fast_exp2(float f) { return __builtin_amdgcn_exp2f(f); }

// async global -> LDS, 16B per lane (dest wave-uniform base; HW adds lane*16B)
static __device__ __forceinline__ void gload16(const bf16* g, bf16* l) {
  __builtin_amdgcn_global_load_lds((__attribute__((address_space(1))) const void*)g,
                                   (__attribute__((address_space(3))) void*)l, 16, 0, 0);
}

// ------------- fused prep: x->bf16 convert + Wqkv^T + Wproj^T -------------
__global__ __launch_bounds__(256)
void k_prep(const float* __restrict__ x, bf16* __restrict__ Xb,
            const float* __restrict__ Wqkv, bf16* __restrict__ WqkvT,
            const float* __restrict__ Wproj, bf16* __restrict__ WprojT)
{
  int bid = blockIdx.x;
  const int tid = threadIdx.x;
  if (bid < 1024) {
    int base = bid * 1024 + tid;
#pragma unroll
    for (int k = 0; k < 4; ++k) {
      int i = base + k * 256;
      float4 v = reinterpret_cast<const float4*>(x)[i];
      bf16 o[4] = { f2b(v.x), f2b(v.y), f2b(v.z), f2b(v.w) };
      reinterpret_cast<uint2*>(Xb)[i] = *reinterpret_cast<uint2*>(o);
    }
    return;
  }
  bid -= 1024;
  __shared__ float tile[32][33];
  const float* W; bf16* WT; int R, Cc, bx, by;
  if (bid < 3072) {
    W = Wqkv;  WT = WqkvT;  R = CC; Cc = 3*CC;
    bx = bid % 96; by = bid / 96;
  } else {
    bid -= 3072;
    W = Wproj; WT = WprojT; R = CC; Cc = CC;
    bx = bid % 32; by = bid / 32;
  }
  int c0 = bx * 32, r0 = by * 32;
  int tx = tid & 31, ty = tid >> 5;
#pragma unroll
  for (int i = 0; i < 4; ++i)
    tile[ty + 8*i][tx] = W[(size_t)(r0 + ty + 8*i) * Cc + c0 + tx];
  __syncthreads();
#pragma unroll
  for (int i = 0; i < 4; ++i)
    WT[(size_t)(c0 + ty + 8*i) * R + r0 + tx] = f2b(tile[tx][ty + 8*i]);
}

// ------------- per-head V (T x D) -> V^T (D x T), bf16 -------------
__global__ void k_vtrans(const bf16* __restrict__ V, bf16* __restrict__ VT) {
  __shared__ bf16 tile[32][33];
  const int bn = blockIdx.z;
  const int d0 = blockIdx.x * 32, t0 = blockIdx.y * 32;
  const size_t base = (size_t)bn * TT * DHEAD;
  int tx = threadIdx.x, ty = threadIdx.y;
#pragma unroll
  for (int i = 0; i < 4; ++i)
    tile[ty + 8*i][tx] = V[base + (size_t)(t0 + ty + 8*i) * DHEAD + d0 + tx];
  __syncthreads();
#pragma unroll
  for (int i = 0; i < 4; ++i)
    VT[base + (size_t)(d0 + ty + 8*i) * TT + t0 + tx] = tile[tx][ty + 8*i];
}

// ============ QKV GEMM (R11, unchanged): 128x256, BK=32, 3-deep + counted vmcnt ============
#define NTK 32
__global__ __launch_bounds__(512, 2)
void k_gemm_qkv(const bf16* __restrict__ Ag, const bf16* __restrict__ Bg,
                const float* __restrict__ bias,
                bf16* __restrict__ Qb, bf16* __restrict__ Kb, bf16* __restrict__ Vb)
{
  const int tid = threadIdx.x;
  const int w = tid >> 6, l = tid & 63;
  const int l16 = l & 15, l4 = l >> 4;
  const int wr = w >> 2, wc = w & 3;

  const int flat = blockIdx.x;
  const int xcd = flat & 7, local = flat >> 3;
  const int bx = (xcd & 1) * 6 + local % 6;
  const int by = (xcd >> 1) * 8 + local / 6;
  const int m0 = by * 128, n0 = bx * 256;

  __shared__ __align__(16) bf16 sm[36864];

  f32x4 acc[4][4];
#pragma unroll
  for (int m = 0; m < 4; ++m)
#pragma unroll
    for (int n = 0; n < 4; ++n) acc[m][n] = 0.f;

  const int srow = tid >> 2;
  const int scol = ((tid & 3) ^ ((tid >> 3) & 3)) * 8;

#define STAGE(buf, kt) do {                                                            \
    const int kb = (kt) * 32 + scol;                                                   \
    gload16(&Ag[(size_t)(m0 +       srow) * CC + kb], &sm[(buf)*12288        + w*512]);\
    gload16(&Bg[(size_t)(n0 +       srow) * CC + kb], &sm[(buf)*12288 + 4096 + w*512]);\
    gload16(&Bg[(size_t)(n0 + 128 + srow) * CC + kb], &sm[(buf)*12288 + 8192 + w*512]);\
  } while (0)

  STAGE(0, 0);
  STAGE(1, 1);
  STAGE(2, 2);
  asm volatile("s_waitcnt vmcnt(6)" ::: "memory");
  __builtin_amdgcn_s_barrier();

  const int slotA = (l4 ^ ((l16 >> 1) & 3)) * 8;
  const int aoff = wr * 2048 + l16 * 32 + slotA;
  const int boff = 4096 + wc * 2048 + l16 * 32 + slotA;

  int rb = 0;
  for (int kt = 0; kt < NTK; ++kt) {
    const int base = rb * 12288;

    bf16x8 af[4], bfr[4];
#pragma unroll
    for (int m = 0; m < 4; ++m)
      af[m] = *reinterpret_cast<const bf16x8*>(&sm[base + aoff + m*512]);
#pragma unroll
    for (int n = 0; n < 4; ++n)
      bfr[n] = *reinterpret_cast<const bf16x8*>(&sm[base + boff + n*512]);
    __builtin_amdgcn_s_setprio(1);
#pragma unroll
    for (int m = 0; m < 4; ++m)
#pragma unroll
      for (int n = 0; n < 4; ++n)
        acc[m][n] = __builtin_amdgcn_mfma_f32_16x16x32_bf16(af[m], bfr[n], acc[m][n], 0, 0, 0);
    __builtin_amdgcn_s_setprio(0);

    __builtin_amdgcn_s_barrier();
    if (kt + 3 < NTK) {
      STAGE(rb, kt + 3);
      asm volatile("s_waitcnt vmcnt(6)" ::: "memory");
    } else if (kt + 2 < NTK) {
      asm volatile("s_waitcnt vmcnt(3)" ::: "memory");
    } else if (kt + 1 < NTK) {
      asm volatile("s_waitcnt vmcnt(0)" ::: "memory");
    }
    __builtin_amdgcn_s_barrier();
    rb = (rb + 1 == 3) ? 0 : rb + 1;
  }
#undef STAGE

  const int ccol = n0 + wc * 64;
  const int which = ccol >> 10;
  bf16* __restrict__ dst = (which == 0) ? Qb : (which == 1) ? Kb : Vb;
  const float qsc = (which == 0) ? 0.125f * 1.4426950408889634f : 1.0f;
#pragma unroll
  for (int m = 0; m < 4; ++m)
#pragma unroll
    for (int n = 0; n < 4; ++n) {
      int gc = ccol + n*16 + l16;
      float bv = bias[gc];
      int c = gc & (CC-1), head = c >> 6, d = c & 63;
#pragma unroll
      for (int j = 0; j < 4; ++j) {
        int gr = m0 + wr*64 + m*16 + l4*4 + j;
        int b = gr >> 11, t = gr & (TT-1);
        dst[(((size_t)b*NHEAD + head)*TT + t)*DHEAD + d] = f2b((acc[m][n][j] + bv) * qsc);
      }
    }
}

// ============ proj GEMM: 128x128 tile, 512 thr / 8 waves, 3-deep + counted vmcnt ============
// per-wave 64x32 output (acc[4][2]); grid 256 = 8 XCDs x 32 bijective.
__global__ __launch_bounds__(512, 1)
void k_gemm_proj(const bf16* __restrict__ Ag, const bf16* __restrict__ Bg,
                 const float* __restrict__ bias, float* __restrict__ outF)
{
  const int tid = threadIdx.x;
  const int w = tid >> 6, l = tid & 63;
  const int l16 = l & 15, l4 = l >> 4;
  const int wr = w >> 2, wc = w & 3;          // 2 x 4 wave grid

  // XCD bijective swizzle: 256 blocks = 8 x 32
  const int flat = blockIdx.x;
  const int swz = (flat & 7) * 32 + (flat >> 3);
  const int bx = swz >> 5, by = swz & 31;     // bx 0..7 (N/128), by 0..31 (M/128)
  const int m0 = by * 128, n0 = bx * 128;

  __shared__ __align__(16) bf16 sm[24576];    // 3 bufs x (A 4096 | B 4096) = 48KB

  f32x4 acc[4][2];
#pragma unroll
  for (int m = 0; m < 4; ++m)
#pragma unroll
    for (int n = 0; n < 2; ++n) acc[m][n] = 0.f;

  const int srow = tid >> 2;                  // 0..127
  const int scol = ((tid & 3) ^ ((tid >> 3) & 3)) * 8;

#define STAGE(buf, kt) do {                                                            \
    const int kb = (kt) * 32 + scol;                                                   \
    gload16(&Ag[(size_t)(m0 + srow) * CC + kb], &sm[(buf)*8192        + w*512]);       \
    gload16(&Bg[(size_t)(n0 + srow) * CC + kb], &sm[(buf)*8192 + 4096 + w*512]);       \
  } while (0)

  STAGE(0, 0);
  STAGE(1, 1);
  STAGE(2, 2);
  asm volatile("s_waitcnt vmcnt(4)" ::: "memory");   // tile0's 2 loads done
  __builtin_amdgcn_s_barrier();

  const int slotA = (l4 ^ ((l16 >> 1) & 3)) * 8;
  const int aoff = wr * 2048 + l16 * 32 + slotA;            // + m*512
  const int boff = 4096 + wc * 1024 + l16 * 32 + slotA;     // + n*512

  int rb = 0;
  for (int kt = 0; kt < NTK; ++kt) {
    const int base = rb * 8192;

    bf16x8 af[4], bfr[2];
#pragma unroll
    for (int m = 0; m < 4; ++m)
      af[m] = *reinterpret_cast<const bf16x8*>(&sm[base + aoff + m*512]);
#pragma unroll
    for (int n = 0; n < 2; ++n)
      bfr[n] = *reinterpret_cast<const bf16x8*>(&sm[base + boff + n*512]);
    __builtin_amdgcn_s_setprio(1);
#pragma unroll
    for (int m = 0; m < 4; ++m)
#pragma unroll
      for (int n = 0; n < 2; ++n)
        acc[m][n] = __builtin_amdgcn_mfma_f32_16x16x32_bf16(af[m], bfr[n], acc[m][n], 0, 0, 0);
    __builtin_amdgcn_s_setprio(0);

    __builtin_amdgcn_s_barrier();
    if (kt + 3 < NTK) {
      STAGE(rb, kt + 3);
      asm volatile("s_waitcnt vmcnt(4)" ::: "memory");   // tile kt+1 landed
    } else if (kt + 2 < NTK) {
      asm volatile("s_waitcnt vmcnt(2)" ::: "memory");
    } else if (kt + 1 < NTK) {
      asm volatile("s_waitcnt vmcnt(0)" ::: "memory");
    }
    __builtin_amdgcn_s_barrier();
    rb = (rb + 1 == 3) ? 0 : rb + 1;
  }
#undef STAGE

#pragma unroll
  for (int m = 0; m < 4; ++m)
#pragma unroll
    for (int n = 0; n < 2; ++n) {
      int gc = n0 + wc*32 + n*16 + l16;
      float bv = bias[gc];
#pragma unroll
      for (int j = 0; j < 4; ++j) {
        int gr = m0 + wr*64 + m*16 + l4*4 + j;
        outF[(size_t)gr * CC + gc] = acc[m][n][j] + bv;
      }
    }
}

// ---------------- flash attention (R9 structure — best measured) ----------------
__global__ __launch_bounds__(512, 2)
void k_attn(const bf16* __restrict__ Qg, const bf16* __restrict__ Kg,
            const bf16* __restrict__ VTg, bf16* __restrict__ Aout)
{
  const int tid  = threadIdx.x;
  const int wave = tid >> 6, lane = tid & 63;
  const int l16 = lane & 15, l4 = lane >> 4;

  const int flat = blockIdx.x;               // 0..511
  const int xcd = flat & 7, i6 = flat >> 3;
  const int bn = xcd*4 + (i6 >> 4);
  const int q0 = (i6 & 15) * 128;
  const int b = bn >> 4, h = bn & (NHEAD-1);

  __shared__ __align__(16) bf16 Ks[KVB][72];
  __shared__ __align__(16) bf16 Vt[DHEAD][136];
  __shared__ __align__(16) bf16 Pl[8][16][136];

  const size_t hb = (size_t)bn * TT * DHEAD;
  const bf16* __restrict__ Kbase = Kg + hb;
  const bf16* __restrict__ Vbase = VTg + hb;

  bf16x8 qf[2];
#pragma unroll
  for (int kk = 0; kk < 2; ++kk)
    qf[kk] = *reinterpret_cast<const bf16x8*>(
        &Qg[hb + (size_t)(q0 + wave*16 + l16) * DHEAD + kk*32 + l4*8]);

  f32x4 o[4];
#pragma unroll
  for (int n = 0; n < 4; ++n) o[n] = 0.f;
  float mrun = -1e30f, lrun = 0.f;

  const int krow = tid >> 2, kcol = (tid & 3) * 16;
  const int vrow = tid >> 3, vcol = (tid & 7) * 16;

  bf16x8 kreg[2], vreg[2];
#pragma unroll
  for (int i = 0; i < 2; ++i) {
    kreg[i] = *reinterpret_cast<const bf16x8*>(&Kbase[(size_t)krow * DHEAD + kcol + 8*i]);
    vreg[i] = *reinterpret_cast<const bf16x8*>(&Vbase[(size_t)vrow * TT + vcol + 8*i]);
  }
#pragma unroll
  for (int i = 0; i < 2; ++i) {
    *reinterpret_cast<bf16x8*>(&Ks[krow][kcol + 8*i]) = kreg[i];
    *reinterpret_cast<bf16x8*>(&Vt[vrow][vcol + 8*i]) = vreg[i];
  }

  for (int t0 = 0; t0 < TT; t0 += KVB) {
    __syncthreads();
    const bool more = (t0 + KVB < TT);
    if (more) {
#pragma unroll
      for (int i = 0; i < 2; ++i) {
        kreg[i] = *reinterpret_cast<const bf16x8*>(
            &Kbase[(size_t)(t0 + KVB + krow) * DHEAD + kcol + 8*i]);
        vreg[i] = *reinterpret_cast<const bf16x8*>(
            &Vbase[(size_t)vrow * TT + t0 + KVB + vcol + 8*i]);
      }
    }

    f32x4 s[8];
#pragma unroll
    for (int n = 0; n < 8; ++n) s[n] = 0.f;
    __builtin_amdgcn_s_setprio(1);
#pragma unroll
    for (int n = 0; n < 8; ++n) {
      bf16x8 kf0 = *reinterpret_cast<const bf16x8*>(&Ks[n*16 + l16][l4*8]);
      bf16x8 kf1 = *reinterpret_cast<const bf16x8*>(&Ks[n*16 + l16][32 + l4*8]);
      s[n] = __builtin_amdgcn_mfma_f32_16x16x32_bf16(kf0, qf[0], s[n], 0, 0, 0);
      s[n] = __builtin_amdgcn_mfma_f32_16x16x32_bf16(kf1, qf[1], s[n], 0, 0, 0);
    }
    __builtin_amdgcn_s_setprio(0);

    float pm = s[0][0];
#pragma unroll
    for (int n = 0; n < 8; ++n)
#pragma unroll
      for (int j = 0; j < 4; ++j) pm = fmaxf(pm, s[n][j]);
    pm = fmaxf(pm, __shfl_xor(pm, 16, 64));
    pm = fmaxf(pm, __shfl_xor(pm, 32, 64));

    if (!__all(pm <= mrun + 8.f)) {
      float mn = fmaxf(mrun, pm);
      float corr = fast_exp2(mrun - mn);
      mrun = mn;
      lrun *= corr;
      float cj[4];
#pragma unroll
      for (int j = 0; j < 4; ++j)
        cj[j] = __shfl(corr, ((lane >> 4) << 2) + j, 64);
#pragma unroll
      for (int n = 0; n < 4; ++n)
#pragma unroll
        for (int j = 0; j < 4; ++j) o[n][j] *= cj[j];
    }

    float psum = 0.f;
#pragma unroll
    for (int n = 0; n < 8; ++n) {
      bf16x4 pk;
#pragma unroll
      for (int j = 0; j < 4; ++j) {
        float pv = fast_exp2(s[n][j] - mrun);
        psum += pv;
        pk[j] = (__bf16)pv;
      }
      *reinterpret_cast<bf16x4*>(&Pl[wave][l16][n*16 + l4*4]) = pk;
    }
    psum += __shfl_xor(psum, 16, 64);
    psum += __shfl_xor(psum, 32, 64);
    lrun += psum;

    bf16x8 pf[4];
#pragma unroll
    for (int kk = 0; kk < 4; ++kk)
      pf[kk] = *reinterpret_cast<const bf16x8*>(&Pl[wave][l16][kk*32 + l4*8]);
    __builtin_amdgcn_s_setprio(1);
#pragma unroll
    for (int n = 0; n < 4; ++n)
#pragma unroll
      for (int kk = 0; kk < 4; ++kk) {
        bf16x8 vf = *reinterpret_cast<const bf16x8*>(&Vt[n*16 + l16][kk*32 + l4*8]);
        o[n] = __builtin_amdgcn_mfma_f32_16x16x32_bf16(pf[kk], vf, o[n], 0, 0, 0);
      }
    __builtin_amdgcn_s_setprio(0);

    __syncthreads();
    if (more) {
#pragma unroll
      for (int i = 0; i < 2; ++i) {
        *reinterpret_cast<bf16x8*>(&Ks[krow][kcol + 8*i]) = kreg[i];
        *reinterpret_cast<bf16x8*>(&Vt[vrow][vcol + 8*i]) = vreg[i];
      }
    }
  }

  float linv = 1.0f / lrun;
  float lj[4];
#pragma unroll
  for (int j = 0; j < 4; ++j)
    lj[j] = __shfl(linv, ((lane >> 4) << 2) + j, 64);
#pragma unroll
  for (int j = 0; j < 4; ++j) {
    int gt = q0 + wave*16 + l4*4 + j;
#pragma unroll
    for (int n = 0; n < 4; ++n)
      Aout[((size_t)(b*TT + gt))*CC + h*DHEAD + n*16 + l16] = f2b(o[n][j] * lj[j]);
  }
}

extern "C" void kernel_launch(void* const* d_in, const int* in_sizes, int n_in,
                              void* d_out, int out_size, void* d_ws, size_t ws_size,
                              hipStream_t stream)
{
  const float* x     = (const float*)d_in[0];
  const float* Wqkv  = (const float*)d_in[1];
  const float* bqkv  = (const float*)d_in[2];
  const float* Wproj = (const float*)d_in[3];
  const float* bproj = (const float*)d_in[4];
  float* out = (float*)d_out;

  char* p = (char*)d_ws;
  bf16* Xb     = (bf16*)p;  p += (size_t)MM*CC*2;
  bf16* WqkvT  = (bf16*)p;  p += (size_t)3*CC*CC*2;
  bf16* WprojT = (bf16*)p;  p += (size_t)CC*CC*2;
  bf16* Qb     = (bf16*)p;  p += (size_t)MM*CC*2;
  bf16* Kb     = (bf16*)p;  p += (size_t)MM*CC*2;
  bf16* Vb     = (bf16*)p;  p += (size_t)MM*CC*2;
  bf16* Attn   = (bf16*)p;  p += (size_t)MM*CC*2;
  bf16* VTb    = Xb;

  k_prep<<<5120, 256, 0, stream>>>(x, Xb, Wqkv, WqkvT, Wproj, WprojT);
  k_gemm_qkv<<<384, 512, 0, stream>>>(Xb, WqkvT, bqkv, Qb, Kb, Vb);
  k_vtrans<<<dim3(DHEAD/32, TT/32, BB*NHEAD), dim3(32, 8), 0, stream>>>(Vb, VTb);
  k_attn<<<512, 512, 0, stream>>>(Qb, Kb, VTb, Attn);
  k_gemm_proj<<<256, 512, 0, stream>>>(Attn, WprojT, bproj, out);
}

// Round 14
// 122.021 us; speedup vs baseline: 1.1390x; 1.0173x over previous
//
#include <hip/hip_runtime.h>
#include <hip/hip_bf16.h>

#define BB 2
#define TT 2048
#define CC 1024
#define NHEAD 16
#define DHEAD 64
#define MM (BB*TT)
#define KVB 128

using bf16 = __hip_bfloat16;
typedef __bf16 bf16x8 __attribute__((ext_vector_type(8)));
typedef __bf16 bf16x4 __attribute__((ext_vector_type(4)));
typedef float f32x4 __attribute__((ext_vector_type(4)));

static __device__ __forceinline__ bf16 f2b(float f) { return __float2bfloat16(f); }
static __device__ __forceinline__ float fast_exp2(float f) { return __builtin_amdgcn_exp2f(f); }

// async global -> LDS, 16B per lane (dest wave-uniform base; HW adds lane*16B)
static __device__ __forceinline__ void gload16(const bf16* g, bf16* l) {
  __builtin_amdgcn_global_load_lds((__attribute__((address_space(1))) const void*)g,
                                   (__attribute__((address_space(3))) void*)l, 16, 0, 0);
}

// ------------- fused prep: x->bf16 convert + Wqkv^T + Wproj^T -------------
__global__ __launch_bounds__(256)
void k_prep(const float* __restrict__ x, bf16* __restrict__ Xb,
            const float* __restrict__ Wqkv, bf16* __restrict__ WqkvT,
            const float* __restrict__ Wproj, bf16* __restrict__ WprojT)
{
  int bid = blockIdx.x;
  const int tid = threadIdx.x;
  if (bid < 1024) {
    int base = bid * 1024 + tid;
#pragma unroll
    for (int k = 0; k < 4; ++k) {
      int i = base + k * 256;
      float4 v = reinterpret_cast<const float4*>(x)[i];
      bf16 o[4] = { f2b(v.x), f2b(v.y), f2b(v.z), f2b(v.w) };
      reinterpret_cast<uint2*>(Xb)[i] = *reinterpret_cast<uint2*>(o);
    }
    return;
  }
  bid -= 1024;
  __shared__ float tile[32][33];
  const float* W; bf16* WT; int R, Cc, bx, by;
  if (bid < 3072) {
    W = Wqkv;  WT = WqkvT;  R = CC; Cc = 3*CC;
    bx = bid % 96; by = bid / 96;
  } else {
    bid -= 3072;
    W = Wproj; WT = WprojT; R = CC; Cc = CC;
    bx = bid % 32; by = bid / 32;
  }
  int c0 = bx * 32, r0 = by * 32;
  int tx = tid & 31, ty = tid >> 5;
#pragma unroll
  for (int i = 0; i < 4; ++i)
    tile[ty + 8*i][tx] = W[(size_t)(r0 + ty + 8*i) * Cc + c0 + tx];
  __syncthreads();
#pragma unroll
  for (int i = 0; i < 4; ++i)
    WT[(size_t)(c0 + ty + 8*i) * R + r0 + tx] = f2b(tile[tx][ty + 8*i]);
}

// ------------- per-head V (T x D) -> V^T (D x T), bf16 -------------
__global__ void k_vtrans(const bf16* __restrict__ V, bf16* __restrict__ VT) {
  __shared__ bf16 tile[32][33];
  const int bn = blockIdx.z;
  const int d0 = blockIdx.x * 32, t0 = blockIdx.y * 32;
  const size_t base = (size_t)bn * TT * DHEAD;
  int tx = threadIdx.x, ty = threadIdx.y;
#pragma unroll
  for (int i = 0; i < 4; ++i)
    tile[ty + 8*i][tx] = V[base + (size_t)(t0 + ty + 8*i) * DHEAD + d0 + tx];
  __syncthreads();
#pragma unroll
  for (int i = 0; i < 4; ++i)
    VT[base + (size_t)(d0 + ty + 8*i) * TT + t0 + tx] = tile[tx][ty + 8*i];
}

// ============ QKV GEMM (R11, unchanged): 128x256, BK=32, 3-deep + counted vmcnt ============
#define NTK 32
__global__ __launch_bounds__(512, 2)
void k_gemm_qkv(const bf16* __restrict__ Ag, const bf16* __restrict__ Bg,
                const float* __restrict__ bias,
                bf16* __restrict__ Qb, bf16* __restrict__ Kb, bf16* __restrict__ Vb)
{
  const int tid = threadIdx.x;
  const int w = tid >> 6, l = tid & 63;
  const int l16 = l & 15, l4 = l >> 4;
  const int wr = w >> 2, wc = w & 3;

  const int flat = blockIdx.x;
  const int xcd = flat & 7, local = flat >> 3;
  const int bx = (xcd & 1) * 6 + local % 6;
  const int by = (xcd >> 1) * 8 + local / 6;
  const int m0 = by * 128, n0 = bx * 256;

  __shared__ __align__(16) bf16 sm[36864];

  f32x4 acc[4][4];
#pragma unroll
  for (int m = 0; m < 4; ++m)
#pragma unroll
    for (int n = 0; n < 4; ++n) acc[m][n] = 0.f;

  const int srow = tid >> 2;
  const int scol = ((tid & 3) ^ ((tid >> 3) & 3)) * 8;

#define STAGE(buf, kt) do {                                                            \
    const int kb = (kt) * 32 + scol;                                                   \
    gload16(&Ag[(size_t)(m0 +       srow) * CC + kb], &sm[(buf)*12288        + w*512]);\
    gload16(&Bg[(size_t)(n0 +       srow) * CC + kb], &sm[(buf)*12288 + 4096 + w*512]);\
    gload16(&Bg[(size_t)(n0 + 128 + srow) * CC + kb], &sm[(buf)*12288 + 8192 + w*512]);\
  } while (0)

  STAGE(0, 0);
  STAGE(1, 1);
  STAGE(2, 2);
  asm volatile("s_waitcnt vmcnt(6)" ::: "memory");
  __builtin_amdgcn_s_barrier();

  const int slotA = (l4 ^ ((l16 >> 1) & 3)) * 8;
  const int aoff = wr * 2048 + l16 * 32 + slotA;
  const int boff = 4096 + wc * 2048 + l16 * 32 + slotA;

  int rb = 0;
  for (int kt = 0; kt < NTK; ++kt) {
    const int base = rb * 12288;

    bf16x8 af[4], bfr[4];
#pragma unroll
    for (int m = 0; m < 4; ++m)
      af[m] = *reinterpret_cast<const bf16x8*>(&sm[base + aoff + m*512]);
#pragma unroll
    for (int n = 0; n < 4; ++n)
      bfr[n] = *reinterpret_cast<const bf16x8*>(&sm[base + boff + n*512]);
    __builtin_amdgcn_s_setprio(1);
#pragma unroll
    for (int m = 0; m < 4; ++m)
#pragma unroll
      for (int n = 0; n < 4; ++n)
        acc[m][n] = __builtin_amdgcn_mfma_f32_16x16x32_bf16(af[m], bfr[n], acc[m][n], 0, 0, 0);
    __builtin_amdgcn_s_setprio(0);

    __builtin_amdgcn_s_barrier();
    if (kt + 3 < NTK) {
      STAGE(rb, kt + 3);
      asm volatile("s_waitcnt vmcnt(6)" ::: "memory");
    } else if (kt + 2 < NTK) {
      asm volatile("s_waitcnt vmcnt(3)" ::: "memory");
    } else if (kt + 1 < NTK) {
      asm volatile("s_waitcnt vmcnt(0)" ::: "memory");
    }
    __builtin_amdgcn_s_barrier();
    rb = (rb + 1 == 3) ? 0 : rb + 1;
  }
#undef STAGE

  const int ccol = n0 + wc * 64;
  const int which = ccol >> 10;
  bf16* __restrict__ dst = (which == 0) ? Qb : (which == 1) ? Kb : Vb;
  const float qsc = (which == 0) ? 0.125f * 1.4426950408889634f : 1.0f;
#pragma unroll
  for (int m = 0; m < 4; ++m)
#pragma unroll
    for (int n = 0; n < 4; ++n) {
      int gc = ccol + n*16 + l16;
      float bv = bias[gc];
      int c = gc & (CC-1), head = c >> 6, d = c & 63;
#pragma unroll
      for (int j = 0; j < 4; ++j) {
        int gr = m0 + wr*64 + m*16 + l4*4 + j;
        int b = gr >> 11, t = gr & (TT-1);
        dst[(((size_t)b*NHEAD + head)*TT + t)*DHEAD + d] = f2b((acc[m][n][j] + bv) * qsc);
      }
    }
}

// ============ proj GEMM (R13, unchanged): 128x128, 512 thr, 3-deep + counted vmcnt ============
__global__ __launch_bounds__(512, 1)
void k_gemm_proj(const bf16* __restrict__ Ag, const bf16* __restrict__ Bg,
                 const float* __restrict__ bias, float* __restrict__ outF)
{
  const int tid = threadIdx.x;
  const int w = tid >> 6, l = tid & 63;
  const int l16 = l & 15, l4 = l >> 4;
  const int wr = w >> 2, wc = w & 3;

  const int flat = blockIdx.x;
  const int swz = (flat & 7) * 32 + (flat >> 3);
  const int bx = swz >> 5, by = swz & 31;
  const int m0 = by * 128, n0 = bx * 128;

  __shared__ __align__(16) bf16 sm[24576];

  f32x4 acc[4][2];
#pragma unroll
  for (int m = 0; m < 4; ++m)
#pragma unroll
    for (int n = 0; n < 2; ++n) acc[m][n] = 0.f;

  const int srow = tid >> 2;
  const int scol = ((tid & 3) ^ ((tid >> 3) & 3)) * 8;

#define STAGE(buf, kt) do {                                                            \
    const int kb = (kt) * 32 + scol;                                                   \
    gload16(&Ag[(size_t)(m0 + srow) * CC + kb], &sm[(buf)*8192        + w*512]);       \
    gload16(&Bg[(size_t)(n0 + srow) * CC + kb], &sm[(buf)*8192 + 4096 + w*512]);       \
  } while (0)

  STAGE(0, 0);
  STAGE(1, 1);
  STAGE(2, 2);
  asm volatile("s_waitcnt vmcnt(4)" ::: "memory");
  __builtin_amdgcn_s_barrier();

  const int slotA = (l4 ^ ((l16 >> 1) & 3)) * 8;
  const int aoff = wr * 2048 + l16 * 32 + slotA;
  const int boff = 4096 + wc * 1024 + l16 * 32 + slotA;

  int rb = 0;
  for (int kt = 0; kt < NTK; ++kt) {
    const int base = rb * 8192;

    bf16x8 af[4], bfr[2];
#pragma unroll
    for (int m = 0; m < 4; ++m)
      af[m] = *reinterpret_cast<const bf16x8*>(&sm[base + aoff + m*512]);
#pragma unroll
    for (int n = 0; n < 2; ++n)
      bfr[n] = *reinterpret_cast<const bf16x8*>(&sm[base + boff + n*512]);
    __builtin_amdgcn_s_setprio(1);
#pragma unroll
    for (int m = 0; m < 4; ++m)
#pragma unroll
      for (int n = 0; n < 2; ++n)
        acc[m][n] = __builtin_amdgcn_mfma_f32_16x16x32_bf16(af[m], bfr[n], acc[m][n], 0, 0, 0);
    __builtin_amdgcn_s_setprio(0);

    __builtin_amdgcn_s_barrier();
    if (kt + 3 < NTK) {
      STAGE(rb, kt + 3);
      asm volatile("s_waitcnt vmcnt(4)" ::: "memory");
    } else if (kt + 2 < NTK) {
      asm volatile("s_waitcnt vmcnt(2)" ::: "memory");
    } else if (kt + 1 < NTK) {
      asm volatile("s_waitcnt vmcnt(0)" ::: "memory");
    }
    __builtin_amdgcn_s_barrier();
    rb = (rb + 1 == 3) ? 0 : rb + 1;
  }
#undef STAGE

#pragma unroll
  for (int m = 0; m < 4; ++m)
#pragma unroll
    for (int n = 0; n < 2; ++n) {
      int gc = n0 + wc*32 + n*16 + l16;
      float bv = bias[gc];
#pragma unroll
      for (int j = 0; j < 4; ++j) {
        int gr = m0 + wr*64 + m*16 + l4*4 + j;
        outF[(size_t)gr * CC + gc] = acc[m][n][j] + bv;
      }
    }
}

// ---------------- flash attention v10: R9 structure + XOR bank-swizzle (T2/G4) ----------------
// LDS tiles unpadded + slot^(row&7) swizzle on 16B slots, applied on BOTH write & read:
//   Ks 128x64 (8 slots/row), Vt 64x128 (16 slots/row), Pl per-wave 16x128 (16 slots/row).
// Verified per-beat: writes <=2-way (free), all b128 reads conflict-free. LDS 64 KB.
__global__ __launch_bounds__(512, 2)
void k_attn(const bf16* __restrict__ Qg, const bf16* __restrict__ Kg,
            const bf16* __restrict__ VTg, bf16* __restrict__ Aout)
{
  const int tid  = threadIdx.x;
  const int wave = tid >> 6, lane = tid & 63;
  const int l16 = lane & 15, l4 = lane >> 4;

  const int flat = blockIdx.x;               // 0..511; 8 XCDs x 64, 4 heads/XCD
  const int xcd = flat & 7, i6 = flat >> 3;
  const int bn = xcd*4 + (i6 >> 4);
  const int q0 = (i6 & 15) * 128;
  const int b = bn >> 4, h = bn & (NHEAD-1);

  __shared__ __align__(16) bf16 KsF[128*64];     // 16 KB
  __shared__ __align__(16) bf16 VtF[64*128];     // 16 KB
  __shared__ __align__(16) bf16 PlF[8*16*128];   // 32 KB

  const size_t hb = (size_t)bn * TT * DHEAD;
  const bf16* __restrict__ Kbase = Kg + hb;
  const bf16* __restrict__ Vbase = VTg + hb;

  bf16x8 qf[2];
#pragma unroll
  for (int kk = 0; kk < 2; ++kk)
    qf[kk] = *reinterpret_cast<const bf16x8*>(
        &Qg[hb + (size_t)(q0 + wave*16 + l16) * DHEAD + kk*32 + l4*8]);

  f32x4 o[4];
#pragma unroll
  for (int n = 0; n < 4; ++n) o[n] = 0.f;
  float mrun = -1e30f, lrun = 0.f;

  // staging geometry: K 128x64 (row tid>>2, slots (tid&3)*2+i), V^T 64x128 (row tid>>3)
  const int krow = tid >> 2, kq = tid & 3;
  const int vrow = tid >> 3, vq = tid & 7;

  bf16x8 kreg[2], vreg[2];
#pragma unroll
  for (int i = 0; i < 2; ++i) {
    kreg[i] = *reinterpret_cast<const bf16x8*>(&Kbase[(size_t)krow * DHEAD + kq*16 + 8*i]);
    vreg[i] = *reinterpret_cast<const bf16x8*>(&Vbase[(size_t)vrow * TT + vq*16 + 8*i]);
  }
#pragma unroll
  for (int i = 0; i < 2; ++i) {
    *reinterpret_cast<bf16x8*>(&KsF[krow*64 + ((kq*2 + i) ^ (krow & 7))*8]) = kreg[i];
    *reinterpret_cast<bf16x8*>(&VtF[vrow*128 + ((vq*2 + i) ^ (vrow & 7))*8]) = vreg[i];
  }

  bf16* PlW = &PlF[wave * 2048];

  for (int t0 = 0; t0 < TT; t0 += KVB) {
    __syncthreads();                      // staged tile visible
    const bool more = (t0 + KVB < TT);
    if (more) {                           // T14: issue next-tile loads now, commit later
#pragma unroll
      for (int i = 0; i < 2; ++i) {
        kreg[i] = *reinterpret_cast<const bf16x8*>(
            &Kbase[(size_t)(t0 + KVB + krow) * DHEAD + kq*16 + 8*i]);
        vreg[i] = *reinterpret_cast<const bf16x8*>(
            &Vbase[(size_t)vrow * TT + t0 + KVB + vq*16 + 8*i]);
      }
    }

    // S^T = K Q^T : lane holds S^T[kv = n*16 + l4*4 + j][q = l16], n = 0..7
    f32x4 s[8];
#pragma unroll
    for (int n = 0; n < 8; ++n) s[n] = 0.f;
    __builtin_amdgcn_s_setprio(1);
#pragma unroll
    for (int n = 0; n < 8; ++n) {
      bf16x8 kf0 = *reinterpret_cast<const bf16x8*>(
          &KsF[(n*16 + l16)*64 + ((l4    ) ^ (l16 & 7))*8]);
      bf16x8 kf1 = *reinterpret_cast<const bf16x8*>(
          &KsF[(n*16 + l16)*64 + ((4 + l4) ^ (l16 & 7))*8]);
      s[n] = __builtin_amdgcn_mfma_f32_16x16x32_bf16(kf0, qf[0], s[n], 0, 0, 0);
      s[n] = __builtin_amdgcn_mfma_f32_16x16x32_bf16(kf1, qf[1], s[n], 0, 0, 0);
    }
    __builtin_amdgcn_s_setprio(0);

    // --- online softmax over 128 kv (exp2 domain), defer-max THR=8 ---
    float pm = s[0][0];
#pragma unroll
    for (int n = 0; n < 8; ++n)
#pragma unroll
      for (int j = 0; j < 4; ++j) pm = fmaxf(pm, s[n][j]);
    pm = fmaxf(pm, __shfl_xor(pm, 16, 64));
    pm = fmaxf(pm, __shfl_xor(pm, 32, 64));

    if (!__all(pm <= mrun + 8.f)) {
      float mn = fmaxf(mrun, pm);
      float corr = fast_exp2(mrun - mn);
      mrun = mn;
      lrun *= corr;
      float cj[4];
#pragma unroll
      for (int j = 0; j < 4; ++j)
        cj[j] = __shfl(corr, ((lane >> 4) << 2) + j, 64);
#pragma unroll
      for (int n = 0; n < 4; ++n)
#pragma unroll
        for (int j = 0; j < 4; ++j) o[n][j] *= cj[j];
    }

    float psum = 0.f;
#pragma unroll
    for (int n = 0; n < 8; ++n) {
      bf16x4 pk;
#pragma unroll
      for (int j = 0; j < 4; ++j) {
        float pv = fast_exp2(s[n][j] - mrun);
        psum += pv;
        pk[j] = (__bf16)pv;
      }
      // logical elems n*16 + l4*4 -> slot 2n + (l4>>1), half (l4&1)
      *reinterpret_cast<bf16x4*>(
          &PlW[l16*128 + ((2*n + (l4 >> 1)) ^ (l16 & 7))*8 + (l4 & 1)*4]) = pk;
    }
    psum += __shfl_xor(psum, 16, 64);
    psum += __shfl_xor(psum, 32, 64);
    lrun += psum;

    // O += P V : A = P[q][kv] (per-wave LDS), B = V^T[d][kv] (LDS)
    bf16x8 pf[4];
#pragma unroll
    for (int kk = 0; kk < 4; ++kk)
      pf[kk] = *reinterpret_cast<const bf16x8*>(
          &PlW[l16*128 + ((4*kk + l4) ^ (l16 & 7))*8]);
    __builtin_amdgcn_s_setprio(1);
#pragma unroll
    for (int n = 0; n < 4; ++n)
#pragma unroll
      for (int kk = 0; kk < 4; ++kk) {
        bf16x8 vf = *reinterpret_cast<const bf16x8*>(
            &VtF[(n*16 + l16)*128 + ((4*kk + l4) ^ (l16 & 7))*8]);
        o[n] = __builtin_amdgcn_mfma_f32_16x16x32_bf16(pf[kk], vf, o[n], 0, 0, 0);
      }
    __builtin_amdgcn_s_setprio(0);

    __syncthreads();                      // all waves done reading Ks/Vt
    if (more) {
#pragma unroll
      for (int i = 0; i < 2; ++i) {
        *reinterpret_cast<bf16x8*>(&KsF[krow*64 + ((kq*2 + i) ^ (krow & 7))*8]) = kreg[i];
        *reinterpret_cast<bf16x8*>(&VtF[vrow*128 + ((vq*2 + i) ^ (vrow & 7))*8]) = vreg[i];
      }
    }
  }

  // epilogue
  float linv = 1.0f / lrun;
  float lj[4];
#pragma unroll
  for (int j = 0; j < 4; ++j)
    lj[j] = __shfl(linv, ((lane >> 4) << 2) + j, 64);
#pragma unroll
  for (int j = 0; j < 4; ++j) {
    int gt = q0 + wave*16 + l4*4 + j;
#pragma unroll
    for (int n = 0; n < 4; ++n)
      Aout[((size_t)(b*TT + gt))*CC + h*DHEAD + n*16 + l16] = f2b(o[n][j] * lj[j]);
  }
}

extern "C" void kernel_launch(void* const* d_in, const int* in_sizes, int n_in,
                              void* d_out, int out_size, void* d_ws, size_t ws_size,
                              hipStream_t stream)
{
  const float* x     = (const float*)d_in[0];
  const float* Wqkv  = (const float*)d_in[1];
  const float* bqkv  = (const float*)d_in[2];
  const float* Wproj = (const float*)d_in[3];
  const float* bproj = (const float*)d_in[4];
  float* out = (float*)d_out;

  char* p = (char*)d_ws;
  bf16* Xb     = (bf16*)p;  p += (size_t)MM*CC*2;
  bf16* WqkvT  = (bf16*)p;  p += (size_t)3*CC*CC*2;
  bf16* WprojT = (bf16*)p;  p += (size_t)CC*CC*2;
  bf16* Qb     = (bf16*)p;  p += (size_t)MM*CC*2;
  bf16* Kb     = (bf16*)p;  p += (size_t)MM*CC*2;
  bf16* Vb     = (bf16*)p;  p += (size_t)MM*CC*2;
  bf16* Attn   = (bf16*)p;  p += (size_t)MM*CC*2;
  bf16* VTb    = Xb;

  k_prep<<<5120, 256, 0, stream>>>(x, Xb, Wqkv, WqkvT, Wproj, WprojT);
  k_gemm_qkv<<<384, 512, 0, stream>>>(Xb, WqkvT, bqkv, Qb, Kb, Vb);
  k_vtrans<<<dim3(DHEAD/32, TT/32, BB*NHEAD), dim3(32, 8), 0, stream>>>(Vb, VTb);
  k_attn<<<512, 512, 0, stream>>>(Qb, Kb, VTb, Attn);
  k_gemm_proj<<<256, 512, 0, stream>>>(Attn, WprojT, bproj, out);
}